// Round 9
// baseline (52.996 us; speedup 1.0000x reference)
//
#include <hip/hip_runtime.h>

// NeighborsConvolution: out[z,a,i] = sum_{b,x,j} [|r_b-r_a|<0.5] * (r_b-r_a)_x * W[x,i,j] * feat[z,b,j]
// B=8, N=1024, CIN=COUT=64.
//
// R9 = MEASUREMENT ROUND (R7 structure + REP=4 pipeline repeat).
// Five structures all plateau at 21-29us while issue-models say 5-14us, and the
// kernel has been invisible to rocprof since R2 (ws-poison fills at 39us own
// the top-5). This round: repeat scan->process->epilogue->store 4x with
// asm-laundered inputs (no CSE across reps; rule #17).
//   dur = F + 4W  (R7: F + W = 22.4)
//   H1 work-bound:  dur ~ 65-75us, counters become visible -> read VALUBusy
//   H2 fixed-bound: dur ~ 30-40us -> F >= 15us, attack launch/ramp next
// Output identical & correct each rep.

#define BATCHSZ 8
#define NPTS 1024
#define CIN 64
#define COUT 64
#define NXJ (3 * CIN)   // 192
#define NG (NXJ / 4)    // 48 float4 groups
#define PPB 8           // points (waves) per block
#define BS (PPB * 64)   // 512
#define GPW (NG / PPB)  // 6 W-groups per wave
#define NSTEP (NPTS / 64)  // 16 ballot steps
#define REP 4

typedef float f32x2 __attribute__((ext_vector_type(2)));

// smem layout (floats):
//  [0,3072)     geo (12KB)           live whole kernel (process re-reads it)
//  [3072,7168)  red[8][8][64] (16KB) live per-rep epilogue
//  [7168,8704)  tmp[8][192] (6KB)
#define SM_RED 3072
#define SM_TMP 7168
#define SM_TOTAL 8704

__global__ __launch_bounds__(256) void transpose_W_kernel(
    const float* __restrict__ W,   // [3][COUT][CIN]
    float* __restrict__ Wt)        // [NG][COUT][4]
{
    const int t = blockIdx.x * 256 + threadIdx.x;
    if (t >= 3 * COUT * CIN) return;
    const int x = t >> 12;
    const int i = (t >> 6) & 63;
    const int j = t & 63;
    const int xj = x * CIN + j;
    Wt[((xj >> 2) * COUT + i) * 4 + (xj & 3)] = W[t];
}

template <bool WT>
__global__ __launch_bounds__(BS, 8) void neigh_conv_kernel(
    const float* __restrict__ feat,  // [B,N,CIN]
    const float* __restrict__ geom,  // [B,N,3]
    const float* __restrict__ Wv,    // WT ? Wt[NG][64][4] : W[3][64][64]
    float* __restrict__ out)         // [B,N,COUT]
{
    const int lane = threadIdx.x & 63;
    const int wv   = threadIdx.x >> 6;
    const int p    = blockIdx.x * PPB + wv;
    const int a    = p & (NPTS - 1);
    const int z    = p >> 10;        // uniform across block (8 | 1024)

    __shared__ __align__(16) float smem[SM_TOTAL];

    // ---- prefetch this wave's W fragment (once; L2 latency hides in stage) ----
    const int g0 = wv * GPW;
    float4 wr[GPW];
    if (WT) {
        const float4* w4 = (const float4*)Wv;
        #pragma unroll
        for (int q = 0; q < GPW; ++q)
            wr[q] = w4[(g0 + q) * COUT + lane];   // coalesced 1KB/instr, L2
    } else {
        #pragma unroll
        for (int q = 0; q < GPW; ++q) {
            const int xj = 4 * (g0 + q);
            wr[q].x = Wv[((xj + 0) >> 6) * 4096 + lane * 64 + ((xj + 0) & 63)];
            wr[q].y = Wv[((xj + 1) >> 6) * 4096 + lane * 64 + ((xj + 1) & 63)];
            wr[q].z = Wv[((xj + 2) >> 6) * 4096 + lane * 64 + ((xj + 2) & 63)];
            wr[q].w = Wv[((xj + 3) >> 6) * 4096 + lane * 64 + ((xj + 3) & 63)];
        }
    }

    // ---- stage geometry (coalesced float4), once ----
    {
        const float4* src = (const float4*)(geom + (size_t)z * NPTS * 3);
        float4* dst = (float4*)smem;
        for (int k = threadIdx.x; k < NPTS * 3 / 4; k += BS)
            dst[k] = src[k];
    }
    __syncthreads();

    const float* geo = smem;
    const float gax0 = geo[a * 3 + 0];
    const float gay0 = geo[a * 3 + 1];
    const float gaz0 = geo[a * 3 + 2];
    const float* fz0 = feat + (size_t)z * NPTS * CIN;

    #pragma unroll 1
    for (int rep = 0; rep < REP; ++rep) {
        // Launder inputs so reps cannot be CSE'd/hoisted (values unchanged).
        float gax = gax0, gay = gay0, gaz = gaz0;
        int zoff = rep;
        asm volatile("" : "+v"(gax), "+v"(gay), "+v"(gaz), "+v"(zoff));
        zoff -= rep;                           // == 0, opaque to optimizer
        const float* fz = fz0 + zoff;

        // ---- scan: 16 ballot steps; masks wave-uniform (SGPRs) ----
        unsigned long long masks[NSTEP];
        #pragma unroll
        for (int ss = 0; ss < NSTEP; ++ss) {
            const int b = ss * 64 + lane;
            float d2;
            {
                // Bit-exact vs numpy near boundary: no contraction, left-assoc.
                #pragma clang fp contract(off)
                const float dx = geo[b * 3 + 0] - gax;   // stride-3: conflict-free
                const float dy = geo[b * 3 + 1] - gay;
                const float dz = geo[b * 3 + 2] - gaz;
                d2 = dx * dx + dy * dy + dz * dz;
            }
            masks[ss] = __ballot(d2 < 0.25f);
        }

        // ---- process: walk masks with scalar ffsll; loads pipelined ----
        float acc0 = 0.f, acc1 = 0.f, acc2 = 0.f;
        #pragma unroll
        for (int ss = 0; ss < NSTEP; ++ss) {
            unsigned long long mm = masks[ss];
            while (mm) {                       // wave-uniform scalar loop
                const int src = __ffsll(mm) - 1;
                mm &= mm - 1ull;
                const int b = ss * 64 + src;   // wave-uniform
                const float gbx = geo[b * 3 + 0];   // uniform addr -> broadcast
                const float gby = geo[b * 3 + 1];
                const float gbz = geo[b * 3 + 2];
                const float dx = gbx - gax;    // bit-identical to scan's diff
                const float dy = gby - gay;
                const float dz = gbz - gaz;
                const float f = fz[(size_t)b * CIN + lane];  // coalesced 256B
                acc0 = fmaf(dx, f, acc0);
                acc1 = fmaf(dy, f, acc1);
                acc2 = fmaf(dz, f, acc2);
            }
        }

        float* tmp = smem + SM_TMP + wv * NXJ;
        tmp[0 * CIN + lane] = acc0;
        tmp[1 * CIN + lane] = acc1;
        tmp[2 * CIN + lane] = acc2;
        __syncthreads();

        // ---- epilogue: wave wv owns W groups [6wv,6wv+6), all 8 points ----
        float* red = smem + SM_RED;   // red[wv*8+pp][i]
        #pragma unroll
        for (int pp = 0; pp < PPB; ++pp) {
            const float4* t4 = (const float4*)(smem + SM_TMP + pp * NXJ);
            f32x2 facc = {0.f, 0.f};
            #pragma unroll
            for (int q = 0; q < GPW; ++q) {
                const float4 t = t4[g0 + q];          // uniform -> LDS broadcast
                f32x2 ta; ta.x = t.x; ta.y = t.y;
                f32x2 tb; tb.x = t.z; tb.y = t.w;
                f32x2 wa; wa.x = wr[q].x; wa.y = wr[q].y;
                f32x2 wb; wb.x = wr[q].z; wb.y = wr[q].w;
                facc = ta * wa + facc;                // v_pk_fma_f32
                facc = tb * wb + facc;
            }
            red[(wv * PPB + pp) * COUT + lane] = facc.x + facc.y;
        }
        __syncthreads();

        float o = 0.f;
        #pragma unroll
        for (int w = 0; w < PPB; ++w)
            o += red[(w * PPB + wv) * COUT + lane];   // 2 lanes/bank: free

        out[(size_t)p * COUT + lane] = o;             // same value every rep
        __syncthreads();   // protect red/tmp before next rep's writes
    }
}

extern "C" void kernel_launch(void* const* d_in, const int* in_sizes, int n_in,
                              void* d_out, int out_size, void* d_ws, size_t ws_size,
                              hipStream_t stream) {
    const float* feat = (const float*)d_in[0];  // [8,1024,64]
    const float* geom = (const float*)d_in[1];  // [8,1024,3]
    const float* W    = (const float*)d_in[2];  // [3,64,64]
    float* out        = (float*)d_out;          // [8,1024,64]

    const int nblocks = BATCHSZ * NPTS / PPB;   // 1024 blocks x 512 threads

    if (ws_size >= (size_t)(3 * COUT * CIN) * sizeof(float)) {
        float* Wt = (float*)d_ws;
        transpose_W_kernel<<<(3 * COUT * CIN + 255) / 256, 256, 0, stream>>>(W, Wt);
        neigh_conv_kernel<true><<<nblocks, BS, 0, stream>>>(feat, geom, Wt, out);
    } else {
        neigh_conv_kernel<false><<<nblocks, BS, 0, stream>>>(feat, geom, W, out);
    }
}

// Round 10
// 18.277 us; speedup vs baseline: 2.8995x; 2.8995x over previous
//
#include <hip/hip_runtime.h>

// NeighborsConvolution: out[z,a,i] = sum_{b,x,j} [|r_b-r_a|<0.5] * (r_b-r_a)_x * W[x,i,j] * feat[z,b,j]
// B=8, N=1024, CIN=COUT=64.
//
// R10 vs R7 (R9 measurement: dur = F + W with F~=12us fixed, W~=10us work):
//  - SINGLE kernel: transpose_W launch + graph dependency eliminated. Each
//    wave's W fragment (6 float4, lane=out-channel) is picked up through the
//    dead red[] LDS region, staged one x-chunk (16KB) at a time in original
//    layout with an XOR-rotate swizzle so stage-writes and strided pickups
//    are conflict-free. 6 prologue barriers, values bit-identical to Wt path.
//  - No d_ws use at all.
//  - Scan/process/epilogue unchanged from R7 (mask-scan in SGPRs, scalar-walk
//    process with pipelined coalesced feat loads, xj-split epilogue).

#define BATCHSZ 8
#define NPTS 1024
#define CIN 64
#define COUT 64
#define NXJ (3 * CIN)      // 192
#define NG (NXJ / 4)       // 48 float4 groups
#define PPB 8              // points (waves) per block
#define BS (PPB * 64)      // 512
#define GPW (NG / PPB)     // 6 W-groups per wave
#define NSTEP (NPTS / 64)  // 16 ballot steps

typedef float f32x2 __attribute__((ext_vector_type(2)));

// smem layout (floats):
//  [0,3072)     geo (12KB)                 live: stage -> end of process
//  [3072,7168)  wstage / red (16KB)        live: prologue staging, then epilogue red
//  [7168,8704)  tmp[8][192] (6KB)
#define SM_RED 3072
#define SM_TMP 7168
#define SM_TOTAL 8704

__global__ __launch_bounds__(BS, 8) void neigh_conv_kernel(
    const float* __restrict__ feat,  // [B,N,CIN]
    const float* __restrict__ geom,  // [B,N,3]
    const float* __restrict__ W,     // [3,COUT,CIN]
    float* __restrict__ out)         // [B,N,COUT]
{
    const int lane = threadIdx.x & 63;
    const int wv   = threadIdx.x >> 6;
    const int p    = blockIdx.x * PPB + wv;
    const int a    = p & (NPTS - 1);
    const int z    = p >> 10;        // uniform across block (8 | 1024)

    __shared__ __align__(16) float smem[SM_TOTAL];

    // ---- stage geometry (coalesced float4) ----
    {
        const float4* src = (const float4*)(geom + (size_t)z * NPTS * 3);
        float4* dst = (float4*)smem;
        for (int k = threadIdx.x; k < NPTS * 3 / 4; k += BS)
            dst[k] = src[k];
    }

    // ---- W fragment pickup via chunked LDS staging (16KB per x-chunk) ----
    // wr[q] = { W[x][lane][4c+e], e=0..3 }  with g = 6*wv+q, x = g>>4, c = g&15
    const int g0 = wv * GPW;
    float4 wr[GPW];
    {
        const float4* w4 = (const float4*)W;          // [3][1024] float4
        float4* ws = (float4*)(smem + SM_RED);        // 1024 float4
        for (int x = 0; x < 3; ++x) {
            __syncthreads();  // x=0: geo+nothing-in-red; x>0: prev pickups done
            // stage chunk x, XOR-rotate swizzle: k=(i*16+j4) -> i*16+((j4+i)&15)
            #pragma unroll
            for (int kk = 0; kk < 2; ++kk) {
                const int k = threadIdx.x + kk * BS;
                const int idx = (k & ~15) | ((k + (k >> 4)) & 15);
                ws[idx] = w4[x * 1024 + k];           // coalesced global read
            }
            __syncthreads();
            #pragma unroll
            for (int q = 0; q < GPW; ++q) {
                const int g = g0 + q;
                if ((g >> 4) == x) {                  // wave-uniform
                    const int c = g & 15;
                    wr[q] = ws[(lane << 4) | ((c + lane) & 15)];  // conflict-free
                }
            }
        }
    }
    // (no barrier needed here: scan reads geo only; red is next written in the
    //  epilogue, which is ordered after the tmp __syncthreads below)

    const float* geo = smem;
    const float gax = geo[a * 3 + 0];
    const float gay = geo[a * 3 + 1];
    const float gaz = geo[a * 3 + 2];
    const float* fz = feat + (size_t)z * NPTS * CIN;

    // ---- scan: 16 ballot steps; masks live wave-uniform (SGPR pairs) ----
    unsigned long long masks[NSTEP];
    #pragma unroll
    for (int ss = 0; ss < NSTEP; ++ss) {
        const int b = ss * 64 + lane;
        float d2;
        {
            // Bit-exact vs numpy near boundary: no contraction, left-assoc.
            #pragma clang fp contract(off)
            const float dx = geo[b * 3 + 0] - gax;   // stride-3: conflict-free
            const float dy = geo[b * 3 + 1] - gay;
            const float dz = geo[b * 3 + 2] - gaz;
            d2 = dx * dx + dy * dy + dz * dz;
        }
        masks[ss] = __ballot(d2 < 0.25f);
    }

    // ---- process: walk masks with scalar ffsll; loads fully pipelined ----
    float acc0 = 0.f, acc1 = 0.f, acc2 = 0.f;
    #pragma unroll
    for (int ss = 0; ss < NSTEP; ++ss) {
        unsigned long long mm = masks[ss];
        while (mm) {                       // wave-uniform scalar loop
            const int src = __ffsll(mm) - 1;
            mm &= mm - 1ull;
            const int b = ss * 64 + src;   // wave-uniform
            const float gbx = geo[b * 3 + 0];   // uniform addr -> broadcast
            const float gby = geo[b * 3 + 1];
            const float gbz = geo[b * 3 + 2];
            const float dx = gbx - gax;    // bit-identical to scan's diff
            const float dy = gby - gay;
            const float dz = gbz - gaz;
            const float f = fz[(size_t)b * CIN + lane];  // coalesced 256B
            acc0 = fmaf(dx, f, acc0);
            acc1 = fmaf(dy, f, acc1);
            acc2 = fmaf(dz, f, acc2);
        }
    }

    float* tmp = smem + SM_TMP + wv * NXJ;
    tmp[0 * CIN + lane] = acc0;
    tmp[1 * CIN + lane] = acc1;
    tmp[2 * CIN + lane] = acc2;
    __syncthreads();   // orders: pickups done, tmp visible; red free to write

    // ---- epilogue: wave wv owns W groups [6wv,6wv+6), all 8 points ----
    float* red = smem + SM_RED;   // red[wv*8+pp][i]
    #pragma unroll
    for (int pp = 0; pp < PPB; ++pp) {
        const float4* t4 = (const float4*)(smem + SM_TMP + pp * NXJ);
        f32x2 facc = {0.f, 0.f};
        #pragma unroll
        for (int q = 0; q < GPW; ++q) {
            const float4 t = t4[g0 + q];          // uniform -> LDS broadcast
            f32x2 ta; ta.x = t.x; ta.y = t.y;
            f32x2 tb; tb.x = t.z; tb.y = t.w;
            f32x2 wa; wa.x = wr[q].x; wa.y = wr[q].y;
            f32x2 wb; wb.x = wr[q].z; wb.y = wr[q].w;
            facc = ta * wa + facc;                // v_pk_fma_f32
            facc = tb * wb + facc;
        }
        red[(wv * PPB + pp) * COUT + lane] = facc.x + facc.y;
    }
    __syncthreads();

    float o = 0.f;
    #pragma unroll
    for (int w = 0; w < PPB; ++w)
        o += red[(w * PPB + wv) * COUT + lane];   // 2 lanes/bank: free

    out[(size_t)p * COUT + lane] = o;
}

extern "C" void kernel_launch(void* const* d_in, const int* in_sizes, int n_in,
                              void* d_out, int out_size, void* d_ws, size_t ws_size,
                              hipStream_t stream) {
    const float* feat = (const float*)d_in[0];  // [8,1024,64]
    const float* geom = (const float*)d_in[1];  // [8,1024,3]
    const float* W    = (const float*)d_in[2];  // [3,64,64]
    float* out        = (float*)d_out;          // [8,1024,64]

    const int nblocks = BATCHSZ * NPTS / PPB;   // 1024 blocks x 512 threads
    neigh_conv_kernel<<<nblocks, BS, 0, stream>>>(feat, geom, W, out);
}